// Round 1
// baseline (133.493 us; speedup 1.0000x reference)
//
#include <hip/hip_runtime.h>

typedef _Float16 f16;
typedef _Float16 f16x8 __attribute__((ext_vector_type(8)));
typedef float v4f __attribute__((ext_vector_type(4)));

// ws layout, f16 units from base:
// [0..16383]      W2T [c=256][k=64]
// [16384..32767]  W0T [f=64][k=256]
// [32768..45055]  WhT [3][f=64][k=64]
// [45056..49151]  Wf1T[f=64][k=64]
// f32 C[3][64] at dword 24576; f32 RPHI[14] at dword 24768
#define WS_W2T  0
#define WS_W0T  16384
#define WS_WHT  32768
#define WS_WF1T 45056
#define WS_CDW  24576
#define WS_RPHI 24768

__global__ __launch_bounds__(256) void preprocess(
    const float* __restrict__ embW1, const float* __restrict__ embW2,
    const float* __restrict__ outW0, const float* __restrict__ outWh,
    const float* __restrict__ outWf1,
    const float* __restrict__ embwa, const float* __restrict__ embwb,
    const float* __restrict__ mixwa, const float* __restrict__ mixwb,
    const float* __restrict__ outwa0, const float* __restrict__ outwb0,
    const float* __restrict__ outwah, const float* __restrict__ outwbh,
    const float* __restrict__ outwaf, const float* __restrict__ outwbf,
    f16* __restrict__ wsh)
{
    const int g = blockIdx.x * 256 + threadIdx.x;
    if (g < 16384) {                       // W2T[c][k] = embW2[k][c]
        const int c = g >> 6, k = g & 63;
        wsh[WS_W2T + g] = (f16)embW2[k*256 + c];
    } else if (g < 32768) {                // W0T[f][k] = outW0[k][f]
        const int i = g - 16384;
        const int f = i >> 8, k = i & 255;
        wsh[WS_W0T + i] = (f16)outW0[k*64 + f];
    } else if (g < 45056) {                // WhT[l][f][k] = outWh[l][k][f]
        const int i = g - 32768;
        const int l = i >> 12, f = (i >> 6) & 63, k = i & 63;
        wsh[WS_WHT + i] = (f16)outWh[l*4096 + k*64 + f];
    } else if (g < 49152) {                // Wf1T[f][k] = outWf1[k][f]
        const int i = g - 45056;
        const int f = i >> 6, k = i & 63;
        wsh[WS_WF1T + i] = (f16)outWf1[k*64 + f];
    } else if (g < 49344) {                // C region factors (symmetric grid collapse)
        const int i = g - 49152;
        const int r = i >> 6, ch = i & 63;
        const float w0 = embW1[ch], w1 = embW1[64 + ch], w2 = embW1[128 + ch];
        float v;
        if (r == 0) {
            v = (1.f + 2.f*__cosf(0.01f*w0)) * (1.f + 2.f*__cosf(0.01f*w1))
              * (1.f + 2.f*__cosf(0.01f*w2)) * (1.f/27.f);
        } else if (r == 1) {
            v = (1.f + 2.f*(__cosf(0.025f*w0) + __cosf(0.05f*w0)))
              * (1.f + 2.f*(__cosf(0.025f*w1) + __cosf(0.05f*w1)))
              * (1.f + 2.f*(__cosf(0.025f*w2) + __cosf(0.05f*w2))) * (1.f/125.f);
        } else {
            v = (1.f + 2.f*(__cosf(0.03f*w0) + __cosf(0.06f*w0) + __cosf(0.09f*w0)))
              * (1.f + 2.f*(__cosf(0.03f*w1) + __cosf(0.06f*w1) + __cosf(0.09f*w1)))
              * (1.f + 2.f*(__cosf(0.03f*w2) + __cosf(0.06f*w2) + __cosf(0.09f*w2))) * (1.f/343.f);
        }
        ((float*)wsh)[WS_CDW + i] = v;
    } else if (g < 49360) {                // RPHI: wa*sin(u)+wb*cos(u) = R*sin(u+phi)
        const int i = g - 49152 - 192;
        const int p = i >> 1;
        float wa, wb;
        switch (p) {
            case 0: wa = embwa[0];  wb = embwb[0];  break;
            case 1: wa = mixwa[0];  wb = mixwb[0];  break;
            case 2: wa = outwa0[0]; wb = outwb0[0]; break;
            case 3: case 4: case 5: wa = outwah[p-3]; wb = outwbh[p-3]; break;
            default: wa = outwaf[0]; wb = outwbf[0]; break;
        }
        const float v = (i & 1) ? atan2f(wb, wa) : sqrtf(wa*wa + wb*wb);
        ((float*)wsh)[WS_RPHI + p*2 + (i & 1)] = v;
    }
}

// Single-wave block: 64 threads process 4 samples. All former inter-wave
// splits (wv) are now in-wave loops; __syncthreads() in a 64-thread block
// compiles to a waitcnt-only fence (no s_barrier, no wave skew).
__global__ __launch_bounds__(64) void model_mfma(
    const float* __restrict__ x, const float* __restrict__ y, const float* __restrict__ t,
    const float* __restrict__ embW1, const float* __restrict__ embb1,
    const float* __restrict__ embb2,
    const float* __restrict__ mixW1, const float* __restrict__ mixb1,
    const float* __restrict__ mixW2, const float* __restrict__ mixb2,
    const float* __restrict__ outb0, const float* __restrict__ outbh,
    const float* __restrict__ outbf1,
    const float* __restrict__ outWf2, const float* __restrict__ outbf2,
    const f16* __restrict__ wsh,
    float* __restrict__ out, int N)
{
    __shared__ __attribute__((aligned(16))) f16 sA[16*72];     // [m=s*4+r][k]
    __shared__ __attribute__((aligned(16))) f16 sE[16*264];    // [s][c] rows 0-3 valid
    __shared__ __attribute__((aligned(16))) f16 sH[2][16*72];  // [s][f] rows 0-3 valid
    __shared__ float sHf[4*65];

    const int lane = threadIdx.x;
    const int n0   = blockIdx.x * 4;
    const float* rphi = (const float*)wsh + WS_RPHI;

    // ---- phase 1: lane = channel k; loop over the block's 4 samples ----
    {
        const int k = lane;
        const float w0 = embW1[k], w1 = embW1[64+k], w2 = embW1[128+k];
        const float b1 = embb1[k];
        const float* Cw = (const float*)wsh + WS_CDW;
        const float c1 = Cw[k], c2 = Cw[64+k], c3 = Cw[128+k];
        const float Re = rphi[0], Pe = rphi[1];
        #pragma unroll
        for (int sq = 0; sq < 4; ++sq) {
            const int ns = (n0 + sq < N) ? (n0 + sq) : (N - 1);
            const float u = fmaf(x[ns], w0, fmaf(y[ns], w1, fmaf(t[ns], w2, b1)));
            const float sv = Re * __sinf(u + Pe);
            f16* row = sA + (sq*4)*72 + k;
            row[0]   = (f16)sv;
            row[72]  = (f16)(sv*c1);
            row[144] = (f16)(sv*c2);
            row[216] = (f16)(sv*c3);
        }
    }
    __syncthreads();

    const int l15 = lane & 15, qb = lane >> 4;

    // ---- phase 2: [16 x 64] @ W2 [64 x 256] over all 16 col-tiles ----
    // C/D: col=lane&15, row=qb*4+reg -> lane holds sample qb, all 4 regions.
    {
        const f16x8 af0 = *(const f16x8*)(sA + l15*72 + qb*8);
        const f16x8 af1 = *(const f16x8*)(sA + l15*72 + 32 + qb*8);
        const float mR = rphi[2], mP = rphi[3], mb2v = mixb2[0];
        #pragma unroll 4
        for (int nt = 0; nt < 16; ++nt) {
            const int cb = nt*16;
            const f16x8 bf0 = *(const f16x8*)(wsh + WS_W2T + (cb + l15)*64 + qb*8);
            const f16x8 bf1 = *(const f16x8*)(wsh + WS_W2T + (cb + l15)*64 + 32 + qb*8);
            v4f acc = {0.f, 0.f, 0.f, 0.f};
            acc = __builtin_amdgcn_mfma_f32_16x16x32_f16(af0, bf0, acc, 0, 0, 0);
            acc = __builtin_amdgcn_mfma_f32_16x16x32_f16(af1, bf1, acc, 0, 0, 0);
            const int c = cb + l15;
            const float b2c = embb2[c];
            const float s0 = acc[0]+b2c, s1 = acc[1]+b2c, s2 = acc[2]+b2c, s3 = acc[3]+b2c;
            float ev = mb2v;
            #pragma unroll
            for (int j = 0; j < 8; ++j) {
                float p = fmaf(s0, mixW1[j],
                          fmaf(s1, mixW1[8+j],
                          fmaf(s2, mixW1[16+j],
                          fmaf(s3, mixW1[24+j], mixb1[j]))));
                ev = fmaf(mR*__sinf(p + mP), mixW2[j], ev);
            }
            sE[qb*264 + c] = (f16)ev;
        }
    }
    __syncthreads();

    // ---- phase 3, layer 0: [4 x 256] @ [256 x 64], 4 feature tiles ----
    // (A rows 4-15 garbage -> affect only their own D rows; store qb==0 only)
    {
        const float R = rphi[4], P = rphi[5];
        #pragma unroll
        for (int ft = 0; ft < 4; ++ft) {
            const int fme = ft*16 + l15;
            v4f acc = {0.f, 0.f, 0.f, 0.f};
            const f16* Ae   = sE + l15*264 + qb*8;
            const f16* W0Tg = wsh + WS_W0T + fme*256 + qb*8;
            #pragma unroll
            for (int kt = 0; kt < 8; ++kt) {
                const f16x8 af = *(const f16x8*)(Ae + kt*32);
                const f16x8 bf = *(const f16x8*)(W0Tg + kt*32);
                acc = __builtin_amdgcn_mfma_f32_16x16x32_f16(af, bf, acc, 0, 0, 0);
            }
            if (qb == 0) {
                const float b0 = outb0[fme];
                #pragma unroll
                for (int r = 0; r < 4; ++r)
                    sH[0][r*72 + fme] = (f16)(R*__sinf(acc[r] + b0 + P));
            }
        }
    }
    __syncthreads();

    // hidden x3 + f1: [4 x 64] @ [64 x 64], 4 feature tiles each
    int cur = 0;
    #pragma unroll
    for (int i = 0; i < 4; ++i) {
        const f16* Wg = (i < 3) ? (wsh + WS_WHT + i*4096) : (wsh + WS_WF1T);
        #pragma unroll
        for (int ft = 0; ft < 4; ++ft) {
            const int fme = ft*16 + l15;
            v4f acc = {0.f, 0.f, 0.f, 0.f};
            #pragma unroll
            for (int kt = 0; kt < 2; ++kt) {
                const f16x8 af = *(const f16x8*)(sH[cur] + l15*72 + kt*32 + qb*8);
                const f16x8 bf = *(const f16x8*)(Wg + fme*64 + kt*32 + qb*8);
                acc = __builtin_amdgcn_mfma_f32_16x16x32_f16(af, bf, acc, 0, 0, 0);
            }
            if (qb == 0) {
                float bias, R, P;
                if (i < 3) { bias = outbh[i*64 + fme]; R = rphi[6+2*i]; P = rphi[7+2*i]; }
                else       { bias = outbf1[fme];       R = rphi[12];    P = rphi[13]; }
                #pragma unroll
                for (int r = 0; r < 4; ++r) {
                    const float v = R*__sinf(acc[r] + bias + P);
                    if (i < 3) sH[cur^1][r*72 + fme] = (f16)v;
                    else       sHf[r*65 + fme] = v;
                }
            }
        }
        __syncthreads();
        cur ^= 1;
    }

    // ---- final 64 -> 3 ----
    if (lane < 12) {
        const int s = lane / 3, o = lane - s*3;
        float a = outbf2[o];
        #pragma unroll 16
        for (int k = 0; k < 64; ++k)
            a = fmaf(sHf[s*65 + k], outWf2[k*3 + o], a);
        const int gn = n0 + s;
        if (gn < N) out[gn*3 + o] = a;
    }
}

extern "C" void kernel_launch(void* const* d_in, const int* in_sizes, int n_in,
                              void* d_out, int out_size, void* d_ws, size_t ws_size,
                              hipStream_t stream) {
    const float* x      = (const float*)d_in[0];
    const float* y      = (const float*)d_in[1];
    const float* t      = (const float*)d_in[2];
    const float* embW1  = (const float*)d_in[3];
    const float* embb1  = (const float*)d_in[4];
    const float* embwa  = (const float*)d_in[5];
    const float* embwb  = (const float*)d_in[6];
    const float* embW2  = (const float*)d_in[7];
    const float* embb2  = (const float*)d_in[8];
    const float* mixW1  = (const float*)d_in[9];
    const float* mixb1  = (const float*)d_in[10];
    const float* mixwa  = (const float*)d_in[11];
    const float* mixwb  = (const float*)d_in[12];
    const float* mixW2  = (const float*)d_in[13];
    const float* mixb2  = (const float*)d_in[14];
    const float* outW0  = (const float*)d_in[15];
    const float* outb0  = (const float*)d_in[16];
    const float* outwa0 = (const float*)d_in[17];
    const float* outwb0 = (const float*)d_in[18];
    const float* outWh  = (const float*)d_in[19];
    const float* outbh  = (const float*)d_in[20];
    const float* outwah = (const float*)d_in[21];
    const float* outwbh = (const float*)d_in[22];
    const float* outWf1 = (const float*)d_in[23];
    const float* outbf1 = (const float*)d_in[24];
    const float* outwaf = (const float*)d_in[25];
    const float* outwbf = (const float*)d_in[26];
    const float* outWf2 = (const float*)d_in[27];
    const float* outbf2 = (const float*)d_in[28];
    float* out = (float*)d_out;
    f16* wsh = (f16*)d_ws;

    const int N = in_sizes[0];

    preprocess<<<193, 256, 0, stream>>>(embW1, embW2, outW0, outWh, outWf1,
                                        embwa, embwb, mixwa, mixwb,
                                        outwa0, outwb0, outwah, outwbh,
                                        outwaf, outwbf, wsh);

    const int blocks = (N + 3) / 4;
    model_mfma<<<blocks, 64, 0, stream>>>(
        x, y, t,
        embW1, embb1, embb2,
        mixW1, mixb1, mixW2, mixb2,
        outb0, outbh, outbf1, outWf2, outbf2,
        wsh, out, N);
}

// Round 2
// 124.982 us; speedup vs baseline: 1.0681x; 1.0681x over previous
//
#include <hip/hip_runtime.h>

typedef _Float16 f16;
typedef _Float16 f16x8 __attribute__((ext_vector_type(8)));
typedef float v4f __attribute__((ext_vector_type(4)));

// ws layout, f16 units from base:
// [0..16383]      W2T [c=256][k=64]
// [16384..32767]  W0T [f=64][k=256]
// [32768..45055]  WhT [3][f=64][k=64]
// [45056..49151]  Wf1T[f=64][k=64]
// f32 C[3][64] at dword 24576; f32 RPHI[14] at dword 24768
#define WS_W2T  0
#define WS_W0T  16384
#define WS_WHT  32768
#define WS_WF1T 45056
#define WS_CDW  24576
#define WS_RPHI 24768

__global__ __launch_bounds__(256) void preprocess(
    const float* __restrict__ embW1, const float* __restrict__ embW2,
    const float* __restrict__ outW0, const float* __restrict__ outWh,
    const float* __restrict__ outWf1,
    const float* __restrict__ embwa, const float* __restrict__ embwb,
    const float* __restrict__ mixwa, const float* __restrict__ mixwb,
    const float* __restrict__ outwa0, const float* __restrict__ outwb0,
    const float* __restrict__ outwah, const float* __restrict__ outwbh,
    const float* __restrict__ outwaf, const float* __restrict__ outwbf,
    f16* __restrict__ wsh)
{
    const int g = blockIdx.x * 256 + threadIdx.x;
    if (g < 16384) {                       // W2T[c][k] = embW2[k][c]
        const int c = g >> 6, k = g & 63;
        wsh[WS_W2T + g] = (f16)embW2[k*256 + c];
    } else if (g < 32768) {                // W0T[f][k] = outW0[k][f]
        const int i = g - 16384;
        const int f = i >> 8, k = i & 255;
        wsh[WS_W0T + i] = (f16)outW0[k*64 + f];
    } else if (g < 45056) {                // WhT[l][f][k] = outWh[l][k][f]
        const int i = g - 32768;
        const int l = i >> 12, f = (i >> 6) & 63, k = i & 63;
        wsh[WS_WHT + i] = (f16)outWh[l*4096 + k*64 + f];
    } else if (g < 49152) {                // Wf1T[f][k] = outWf1[k][f]
        const int i = g - 45056;
        const int f = i >> 6, k = i & 63;
        wsh[WS_WF1T + i] = (f16)outWf1[k*64 + f];
    } else if (g < 49344) {                // C region factors (symmetric grid collapse)
        const int i = g - 49152;
        const int r = i >> 6, ch = i & 63;
        const float w0 = embW1[ch], w1 = embW1[64 + ch], w2 = embW1[128 + ch];
        float v;
        if (r == 0) {
            v = (1.f + 2.f*__cosf(0.01f*w0)) * (1.f + 2.f*__cosf(0.01f*w1))
              * (1.f + 2.f*__cosf(0.01f*w2)) * (1.f/27.f);
        } else if (r == 1) {
            v = (1.f + 2.f*(__cosf(0.025f*w0) + __cosf(0.05f*w0)))
              * (1.f + 2.f*(__cosf(0.025f*w1) + __cosf(0.05f*w1)))
              * (1.f + 2.f*(__cosf(0.025f*w2) + __cosf(0.05f*w2))) * (1.f/125.f);
        } else {
            v = (1.f + 2.f*(__cosf(0.03f*w0) + __cosf(0.06f*w0) + __cosf(0.09f*w0)))
              * (1.f + 2.f*(__cosf(0.03f*w1) + __cosf(0.06f*w1) + __cosf(0.09f*w1)))
              * (1.f + 2.f*(__cosf(0.03f*w2) + __cosf(0.06f*w2) + __cosf(0.09f*w2))) * (1.f/343.f);
        }
        ((float*)wsh)[WS_CDW + i] = v;
    } else if (g < 49360) {                // RPHI: wa*sin(u)+wb*cos(u) = R*sin(u+phi)
        const int i = g - 49344;
        const int p = i >> 1;
        float wa, wb;
        switch (p) {
            case 0: wa = embwa[0];  wb = embwb[0];  break;
            case 1: wa = mixwa[0];  wb = mixwb[0];  break;
            case 2: wa = outwa0[0]; wb = outwb0[0]; break;
            case 3: case 4: case 5: wa = outwah[p-3]; wb = outwbh[p-3]; break;
            default: wa = outwaf[0]; wb = outwbf[0]; break;
        }
        const float v = (i & 1) ? atan2f(wb, wa) : sqrtf(wa*wa + wb*wb);
        ((float*)wsh)[WS_RPHI + p*2 + (i & 1)] = v;
    }
}

__global__ __launch_bounds__(256, 4) void model_mfma(
    const float* __restrict__ x, const float* __restrict__ y, const float* __restrict__ t,
    const float* __restrict__ embW1, const float* __restrict__ embb1,
    const float* __restrict__ embb2,
    const float* __restrict__ mixW1, const float* __restrict__ mixb1,
    const float* __restrict__ mixW2, const float* __restrict__ mixb2,
    const float* __restrict__ outb0, const float* __restrict__ outbh,
    const float* __restrict__ outbf1,
    const float* __restrict__ outWf2, const float* __restrict__ outbf2,
    const f16* __restrict__ wsh,
    float* __restrict__ out, int N)
{
    __shared__ __attribute__((aligned(16))) f16 sA[16*72];     // [m=s*4+r][k]
    __shared__ __attribute__((aligned(16))) f16 sE[16*264];    // [s][c] rows 0-3 valid
    __shared__ __attribute__((aligned(16))) f16 sH[2][16*72];  // [s][f] rows 0-3 valid
    __shared__ float sHf[4*65];

    const int tid  = threadIdx.x;
    const int lane = tid & 63;
    const int wv   = tid >> 6;
    const int n0   = blockIdx.x * 4;
    const float* rphi = (const float*)wsh + WS_RPHI;

    // ---- phase 1: wave sq computes sample sq; lane = channel k ----
    {
        const int k = lane, sq = wv;
        const float w0 = embW1[k], w1 = embW1[64+k], w2 = embW1[128+k];
        const float b1 = embb1[k];
        const float* Cw = (const float*)wsh + WS_CDW;
        const float c1 = Cw[k], c2 = Cw[64+k], c3 = Cw[128+k];
        const int ns = (n0 + sq < N) ? (n0 + sq) : (N - 1);
        const float u = fmaf(x[ns], w0, fmaf(y[ns], w1, fmaf(t[ns], w2, b1)));
        const float sv = rphi[0] * __sinf(u + rphi[1]);
        f16* row = sA + (sq*4)*72 + k;
        row[0]   = (f16)sv;
        row[72]  = (f16)(sv*c1);
        row[144] = (f16)(sv*c2);
        row[216] = (f16)(sv*c3);
    }
    __syncthreads();

    const int l15 = lane & 15, qb = lane >> 4;

    // ---- phase 2: [16 x 64] @ W2 [64 x 256]; wave wv owns cols wv*64..+63 ----
    // C/D: col=lane&15, row=qb*4+reg -> lane holds sample qb, all 4 regions.
    {
        const f16x8 af0 = *(const f16x8*)(sA + l15*72 + qb*8);
        const f16x8 af1 = *(const f16x8*)(sA + l15*72 + 32 + qb*8);
        const float mR = rphi[2], mP = rphi[3], mb2v = mixb2[0];
        #pragma unroll
        for (int nt = 0; nt < 4; ++nt) {
            const int cb = wv*64 + nt*16;
            const f16x8 bf0 = *(const f16x8*)(wsh + WS_W2T + (cb + l15)*64 + qb*8);
            const f16x8 bf1 = *(const f16x8*)(wsh + WS_W2T + (cb + l15)*64 + 32 + qb*8);
            v4f acc = {0.f, 0.f, 0.f, 0.f};
            acc = __builtin_amdgcn_mfma_f32_16x16x32_f16(af0, bf0, acc, 0, 0, 0);
            acc = __builtin_amdgcn_mfma_f32_16x16x32_f16(af1, bf1, acc, 0, 0, 0);
            const int c = cb + l15;
            const float b2c = embb2[c];
            const float s0 = acc[0]+b2c, s1 = acc[1]+b2c, s2 = acc[2]+b2c, s3 = acc[3]+b2c;
            float ev = mb2v;
            #pragma unroll
            for (int j = 0; j < 8; ++j) {
                float p = fmaf(s0, mixW1[j],
                          fmaf(s1, mixW1[8+j],
                          fmaf(s2, mixW1[16+j],
                          fmaf(s3, mixW1[24+j], mixb1[j]))));
                ev = fmaf(mR*__sinf(p + mP), mixW2[j], ev);
            }
            sE[qb*264 + c] = (f16)ev;
        }
    }
    __syncthreads();

    // ---- phase 3: wave wv owns feature tile fme = wv*16 + l15 ----
    const int fme = wv*16 + l15;

    // layer 0: [4 x 256] @ [256 x 64] (A rows 4-15 garbage -> rows only affect
    // their own D rows; store qb==0 only)
    {
        v4f acc = {0.f, 0.f, 0.f, 0.f};
        const f16* Ae   = sE + l15*264 + qb*8;
        const f16* W0Tg = wsh + WS_W0T + fme*256 + qb*8;
        #pragma unroll
        for (int kt = 0; kt < 8; ++kt) {
            const f16x8 af = *(const f16x8*)(Ae + kt*32);
            const f16x8 bf = *(const f16x8*)(W0Tg + kt*32);
            acc = __builtin_amdgcn_mfma_f32_16x16x32_f16(af, bf, acc, 0, 0, 0);
        }
        if (qb == 0) {
            const float b0 = outb0[fme], R = rphi[4], P = rphi[5];
            #pragma unroll
            for (int r = 0; r < 4; ++r)
                sH[0][r*72 + fme] = (f16)(R*__sinf(acc[r] + b0 + P));
        }
    }
    __syncthreads();

    // hidden x3 + f1: [4 x 64] @ [64 x 64]
    int cur = 0;
    #pragma unroll
    for (int i = 0; i < 4; ++i) {
        const f16* Wg = (i < 3) ? (wsh + WS_WHT + i*4096) : (wsh + WS_WF1T);
        v4f acc = {0.f, 0.f, 0.f, 0.f};
        #pragma unroll
        for (int kt = 0; kt < 2; ++kt) {
            const f16x8 af = *(const f16x8*)(sH[cur] + l15*72 + kt*32 + qb*8);
            const f16x8 bf = *(const f16x8*)(Wg + fme*64 + kt*32 + qb*8);
            acc = __builtin_amdgcn_mfma_f32_16x16x32_f16(af, bf, acc, 0, 0, 0);
        }
        if (qb == 0) {
            float bias, R, P;
            if (i < 3) { bias = outbh[i*64 + fme]; R = rphi[6+2*i]; P = rphi[7+2*i]; }
            else       { bias = outbf1[fme];       R = rphi[12];    P = rphi[13]; }
            #pragma unroll
            for (int r = 0; r < 4; ++r) {
                const float v = R*__sinf(acc[r] + bias + P);
                if (i < 3) sH[cur^1][r*72 + fme] = (f16)v;
                else       sHf[r*65 + fme] = v;
            }
        }
        __syncthreads();
        cur ^= 1;
    }

    // ---- final 64 -> 3 ----
    if (tid < 12) {
        const int s = tid / 3, o = tid - s*3;
        float a = outbf2[o];
        #pragma unroll 16
        for (int k = 0; k < 64; ++k)
            a = fmaf(sHf[s*65 + k], outWf2[k*3 + o], a);
        const int gn = n0 + s;
        if (gn < N) out[gn*3 + o] = a;
    }
}

extern "C" void kernel_launch(void* const* d_in, const int* in_sizes, int n_in,
                              void* d_out, int out_size, void* d_ws, size_t ws_size,
                              hipStream_t stream) {
    const float* x      = (const float*)d_in[0];
    const float* y      = (const float*)d_in[1];
    const float* t      = (const float*)d_in[2];
    const float* embW1  = (const float*)d_in[3];
    const float* embb1  = (const float*)d_in[4];
    const float* embwa  = (const float*)d_in[5];
    const float* embwb  = (const float*)d_in[6];
    const float* embW2  = (const float*)d_in[7];
    const float* embb2  = (const float*)d_in[8];
    const float* mixW1  = (const float*)d_in[9];
    const float* mixb1  = (const float*)d_in[10];
    const float* mixwa  = (const float*)d_in[11];
    const float* mixwb  = (const float*)d_in[12];
    const float* mixW2  = (const float*)d_in[13];
    const float* mixb2  = (const float*)d_in[14];
    const float* outW0  = (const float*)d_in[15];
    const float* outb0  = (const float*)d_in[16];
    const float* outwa0 = (const float*)d_in[17];
    const float* outwb0 = (const float*)d_in[18];
    const float* outWh  = (const float*)d_in[19];
    const float* outbh  = (const float*)d_in[20];
    const float* outwah = (const float*)d_in[21];
    const float* outwbh = (const float*)d_in[22];
    const float* outWf1 = (const float*)d_in[23];
    const float* outbf1 = (const float*)d_in[24];
    const float* outwaf = (const float*)d_in[25];
    const float* outwbf = (const float*)d_in[26];
    const float* outWf2 = (const float*)d_in[27];
    const float* outbf2 = (const float*)d_in[28];
    float* out = (float*)d_out;
    f16* wsh = (f16*)d_ws;

    const int N = in_sizes[0];

    preprocess<<<193, 256, 0, stream>>>(embW1, embW2, outW0, outWh, outWf1,
                                        embwa, embwb, mixwa, mixwb,
                                        outwa0, outwb0, outwah, outwbh,
                                        outwaf, outwbf, wsh);

    const int blocks = (N + 3) / 4;
    model_mfma<<<blocks, 256, 0, stream>>>(
        x, y, t,
        embW1, embb1, embb2,
        mixW1, mixb1, mixW2, mixb2,
        outb0, outbh, outbf1, outWf2, outbf2,
        wsh, out, N);
}